// Round 5
// baseline (124.195 us; speedup 1.0000x reference)
//
#include <hip/hip_runtime.h>
#include <math.h>

#define SN  512
#define NN  128
#define CIN 32
#define CA  5
#define HH  64
#define YY  96
#define H3  128
#define H4  64
#define EPSF 1e-7f

typedef __attribute__((ext_vector_type(8))) short  bf16x8;
typedef __attribute__((ext_vector_type(4))) float  f32x4;
typedef __attribute__((ext_vector_type(4))) unsigned short us4;

__device__ inline unsigned short f2b(float f) {
    unsigned u = __builtin_bit_cast(unsigned, f);
    return (unsigned short)((u + 0x7FFFu + ((u >> 16) & 1u)) >> 16);
}
__device__ inline float b2f(unsigned short h) {
    unsigned u = ((unsigned)h) << 16;
    return __builtin_bit_cast(float, u);
}
__device__ inline bf16x8 pack8(float4 f0, float4 f1) {
    bf16x8 v;
    v[0]=(short)f2b(f0.x); v[1]=(short)f2b(f0.y); v[2]=(short)f2b(f0.z); v[3]=(short)f2b(f0.w);
    v[4]=(short)f2b(f1.x); v[5]=(short)f2b(f1.y); v[6]=(short)f2b(f1.z); v[7]=(short)f2b(f1.w);
    return v;
}

// ws pack (bf16): W1p [c5][b64][a32] @0 (10240) | W2p [c5][b64][a96] @10240 (30720)
//                 nwp [b128][a96] @40960 (12288). c=4 is the LW linear channel.
__global__ __launch_bounds__(512) void pack_weights(
    const float* __restrict__ w1, const float* __restrict__ lw1,
    const float* __restrict__ w2, const float* __restrict__ lw2,
    const float* __restrict__ nw, unsigned short* __restrict__ wp)
{
    int t = blockIdx.x*512 + threadIdx.x;
    if (t < 10240) {
        int c = t >> 11, rem = t & 2047, b = rem >> 5, a = rem & 31;
        float v = (c < 4) ? w1[(a*64+b)*4 + c] : lw1[a*64+b];
        wp[t] = f2b(v);
    } else if (t < 40960) {
        int u = t - 10240;
        int c = u / 6144, rem = u % 6144, b = rem / 96, a = rem % 96;
        float v = (c < 4) ? w2[(a*64+b)*4 + c] : lw2[a*64+b];
        wp[t] = f2b(v);
    } else {
        int u = t - 40960;
        int b = u / 96, a = u % 96;
        wp[t] = f2b(nw[a*128 + b]);
    }
}

// One conv stage. PZ = 256 rows x 128 shorts, XOR-swizzled 16B chunks.
// W frags from global wp. pc4 = linear channel (f32, regs).
template<int CINY, bool FIRST>
__device__ __forceinline__ void conv_core(
    const unsigned short* __restrict__ wp, const float* __restrict__ LB,
    short* PZ, float* invL, const bf16x8 (&Af)[4][4],
    bf16x8 a0, bf16x8 a1, bf16x8 a2,
    float (&v)[4][4], int wave, int lm, int kg)
{
    constexpr int K32  = CINY / 32;
    constexpr int WOFF = (CINY == 32) ? 0 : 10240;
    f32x4 pc4[4];
    {
        bf16x8 af[3] = {a0, a1, a2};
        #pragma unroll
        for (int c = 0; c < 5; ++c) {
            f32x4 pc[4];
            #pragma unroll
            for (int n = 0; n < 4; ++n) pc[n] = (f32x4){0.f,0.f,0.f,0.f};
            #pragma unroll
            for (int ks = 0; ks < K32; ++ks) {
                #pragma unroll
                for (int n = 0; n < 4; ++n) {
                    const bf16x8 bw = *(const bf16x8*)&wp[WOFF + (c*64 + n*16 + lm)*CINY + ks*32 + kg*8];
                    pc[n] = __builtin_amdgcn_mfma_f32_16x16x32_bf16(af[ks], bw, pc[n], 0,0,0);
                }
            }
            if (c < 4) {
                #pragma unroll
                for (int n = 0; n < 4; ++n) {
                    const int row = c*64 + n*16 + lm;
                    const int byo = (wave*32 + kg*8) ^ ((row & 7) << 4);
                    us4 w;
                    w[0]=f2b(pc[n][0]); w[1]=f2b(pc[n][1]); w[2]=f2b(pc[n][2]); w[3]=f2b(pc[n][3]);
                    *(us4*)&PZ[row*128 + (byo >> 1)] = w;
                }
            } else {
                #pragma unroll
                for (int n = 0; n < 4; ++n) pc4[n] = pc[n];
            }
        }
    }
    __syncthreads();

    bf16x8 ones;
    #pragma unroll
    for (int q = 0; q < 8; ++q) ones[q] = (short)0x3F80;
    float invr[4][4];
    #pragma unroll
    for (int nh = 0; nh < 2; ++nh) {
        f32x4 acc[4][2];
        #pragma unroll
        for (int c=0;c<4;++c)
            #pragma unroll
            for (int n2=0;n2<2;++n2) acc[c][n2] = (f32x4){0.f,0.f,0.f,0.f};
        f32x4 sums[4];
        if (FIRST && nh == 0) {
            #pragma unroll
            for (int c=0;c<4;++c) sums[c] = (f32x4){0.f,0.f,0.f,0.f};
        }
        #pragma unroll
        for (int jt = 0; jt < 4; ++jt) {
            #pragma unroll
            for (int c = 0; c < 4; ++c) {
                #pragma unroll
                for (int n2 = 0; n2 < 2; ++n2) {
                    const int row = c*64 + (nh*2+n2)*16 + lm;
                    const int byo = (jt*64 + kg*16) ^ ((row & 7) << 4);
                    const bf16x8 bp = *(const bf16x8*)&PZ[row*128 + (byo >> 1)];
                    acc[c][n2] = __builtin_amdgcn_mfma_f32_16x16x32_bf16(Af[jt][c], bp, acc[c][n2], 0,0,0);
                }
                if (FIRST && nh == 0)
                    sums[c] = __builtin_amdgcn_mfma_f32_16x16x32_bf16(Af[jt][c], ones, sums[c], 0,0,0);
            }
        }
        if (FIRST && nh == 0) {
            #pragma unroll
            for (int c=0;c<4;++c)
                #pragma unroll
                for (int r=0;r<4;++r) invr[c][r] = 1.0f/(sums[c][r] + EPSF);
            if (lm == 0) {
                #pragma unroll
                for (int r=0;r<4;++r)
                    #pragma unroll
                    for (int c=0;c<4;++c)
                        invL[(wave*16 + kg*4 + r)*4 + c] = invr[c][r];
            }
        }
        #pragma unroll
        for (int n2 = 0; n2 < 2; ++n2) {
            const int n = nh*2 + n2;
            const float lbv = LB[n*16 + lm];
            #pragma unroll
            for (int r = 0; r < 4; ++r) {
                float vv = lbv + pc4[n][r];
                if constexpr (FIRST) {
                    #pragma unroll
                    for (int c=0;c<4;++c) vv += acc[c][n2][r]*invr[c][r];
                } else {
                    const f32x4 iv = *(const f32x4*)&invL[(wave*16 + kg*4 + r)*4];
                    #pragma unroll
                    for (int c=0;c<4;++c) vv += acc[c][n2][r]*iv[c];
                }
                v[n][r] = tanhf(vv);
            }
        }
    }
}

__global__ __launch_bounds__(512, 4) void fused_kernel(
    const float* __restrict__ A, const float* __restrict__ x,
    const unsigned short* __restrict__ wp,
    const float* __restrict__ lb1, const float* __restrict__ lb2,
    const float* __restrict__ gw, const float* __restrict__ gb,
    const float* __restrict__ nb,
    const float* __restrict__ l3w, const float* __restrict__ l3b,
    const float* __restrict__ l4w, const float* __restrict__ l4b,
    const float* __restrict__ l5w, const float* __restrict__ l5b,
    float* __restrict__ out)
{
    __shared__ __align__(16) char smem[67584];
    short* PZ   = (short*)smem;                   // 256 rows x 128 sh (64 KB)
    float* invL = (float*)(smem + 65536);         // [128][4] f32
    short* xcb  = (short*)smem;                   // pool alias: [128][104]
    float* gate = (float*)(smem + 26624);
    float* red  = (float*)(smem + 27136);
    float* tmpv = (float*)(smem + 27648);
    float* part = (float*)(smem + 28160);         // [8][128] f32

    const int s = blockIdx.x, tid = threadIdx.x;
    const int wave = tid>>6, lane = tid&63, lm = lane&15, kg = lane>>4;
    const float* xg = x + (size_t)s*NN*CIN;

    // x fragment for P-GEMMs (row jrow)
    const int jrow = wave*16 + lm;
    bf16x8 xfrag;
    {
        float4 f0 = *(const float4*)(xg + jrow*CIN + kg*8);
        float4 f1 = *(const float4*)(xg + jrow*CIN + kg*8 + 4);
        xfrag = pack8(f0, f1);
    }

    // ===== A prepass: coalesced float4 loads -> wave-private LDS -> Af frags =====
    bf16x8 Af[4][4];
    {
        short* scr = PZ + wave*2688;              // [16][168]
        const float* Ab = A + ((size_t)s*NN + wave*16)*NN*CA;
        const int r8 = lane>>3, l8 = lane&7;
        #pragma unroll
        for (int jt = 0; jt < 4; ++jt) {
            #pragma unroll
            for (int rh = 0; rh < 2; ++rh) {
                const int r = r8 + rh*8;
                const float* rp = Ab + (size_t)r*(NN*CA) + jt*160 + l8*20;
                float4 q0 = *(const float4*)(rp);
                float4 q1 = *(const float4*)(rp+4);
                float4 q2 = *(const float4*)(rp+8);
                float4 q3 = *(const float4*)(rp+12);
                float4 q4 = *(const float4*)(rp+16);
                short* lr = scr + r*168;
                const int jb = 4*l8;
                lr[0*40 + jb+0] = (short)f2b(q0.x);
                lr[1*40 + jb+0] = (short)f2b(q0.y);
                lr[2*40 + jb+0] = (short)f2b(q0.z);
                lr[3*40 + jb+0] = (short)f2b(q0.w);
                lr[0*40 + jb+1] = (short)f2b(q1.y);
                lr[1*40 + jb+1] = (short)f2b(q1.z);
                lr[2*40 + jb+1] = (short)f2b(q1.w);
                lr[3*40 + jb+1] = (short)f2b(q2.x);
                lr[0*40 + jb+2] = (short)f2b(q2.z);
                lr[1*40 + jb+2] = (short)f2b(q2.w);
                lr[2*40 + jb+2] = (short)f2b(q3.x);
                lr[3*40 + jb+2] = (short)f2b(q3.y);
                lr[0*40 + jb+3] = (short)f2b(q3.w);
                lr[1*40 + jb+3] = (short)f2b(q4.x);
                lr[2*40 + jb+3] = (short)f2b(q4.y);
                lr[3*40 + jb+3] = (short)f2b(q4.z);
            }
            #pragma unroll
            for (int c = 0; c < 4; ++c)
                Af[jt][c] = *(const bf16x8*)&scr[lm*168 + c*40 + kg*8];
        }
    }
    __syncthreads();

    // ===== conv1 =====
    float v[4][4];
    conv_core<CIN, true>(wp, lb1, PZ, invL, Af, xfrag, xfrag, xfrag, v, wave, lm, kg);
    __syncthreads();                               // all PZ (P1) reads done

    // h1 bounce (wave-private): (i,b)-regs -> (j,a)-frags
    bf16x8 h0, h1f;
    {
        short* scr = PZ + wave*2688;
        #pragma unroll
        for (int n=0;n<4;++n)
            #pragma unroll
            for (int r=0;r<4;++r)
                scr[(kg*4+r)*72 + n*16 + lm] = (short)f2b(v[n][r]);
        h0  = *(const bf16x8*)&scr[lm*72 + kg*8];
        h1f = *(const bf16x8*)&scr[lm*72 + 32 + kg*8];
    }
    __syncthreads();                               // h1 reads done before P2 writes

    // ===== conv2 =====
    conv_core<YY, false>(wp, lb2, PZ, invL, Af, h0, h1f, xfrag, v, wave, lm, kg);
    __syncthreads();                               // PZ (P2) reads done -> pool alias

    // ===== pool + head =====
    #pragma unroll
    for (int n=0;n<4;++n)
        #pragma unroll
        for (int r=0;r<4;++r)
            xcb[(wave*16 + kg*4 + r)*104 + n*16 + lm] = (short)f2b(v[n][r]);
    for (int t = tid; t < NN*CIN; t += 512)
        xcb[(t>>5)*104 + 64 + (t&31)] = (short)f2b(xg[t]);
    __syncthreads();

    float z = 0.f, e = 0.f;
    if (tid < NN) {
        z = gb[0];
        for (int a = 0; a < YY; ++a) z += b2f((unsigned short)xcb[tid*104 + a]) * gw[a];
        red[tid] = z;
    }
    __syncthreads();
    for (int off = 64; off > 0; off >>= 1) {
        if (tid < off) red[tid] = fmaxf(red[tid], red[tid + off]);
        __syncthreads();
    }
    const float zmax = red[0];
    __syncthreads();
    if (tid < NN) { e = expf(z - zmax); red[tid] = e; }
    __syncthreads();
    for (int off = 64; off > 0; off >>= 1) {
        if (tid < off) red[tid] += red[tid + off];
        __syncthreads();
    }
    const float gsum = red[0];
    __syncthreads();
    if (tid < NN) gate[tid] = e / gsum;
    __syncthreads();

    {
        f32x4 pacc[8];
        #pragma unroll
        for (int nt=0;nt<8;++nt) pacc[nt] = (f32x4){0.f,0.f,0.f,0.f};
        #pragma unroll
        for (int ks=0;ks<3;++ks) {
            const bf16x8 afp = *(const bf16x8*)&xcb[(wave*16+lm)*104 + ks*32 + kg*8];
            #pragma unroll
            for (int nt=0;nt<8;++nt) {
                const bf16x8 bfp = *(const bf16x8*)&wp[40960 + (nt*16+lm)*96 + ks*32 + kg*8];
                pacc[nt] = __builtin_amdgcn_mfma_f32_16x16x32_bf16(afp, bfp, pacc[nt], 0,0,0);
            }
        }
        #pragma unroll
        for (int nt=0;nt<8;++nt) {
            const float nbv = nb[nt*16+lm];
            float p = 0.f;
            #pragma unroll
            for (int r=0;r<4;++r)
                p += gate[wave*16 + kg*4 + r] * tanhf(pacc[nt][r] + nbv);
            p += __shfl_xor(p, 16);
            p += __shfl_xor(p, 32);
            if (lane < 16) part[wave*128 + nt*16 + lm] = p;
        }
    }
    __syncthreads();
    if (tid < H3) {
        float pooled = 0.f;
        #pragma unroll
        for (int w = 0; w < 8; ++w) pooled += part[w*128 + tid];
        tmpv[tid] = tanhf(pooled);                 // h3
    }
    __syncthreads();
    if (tid < H3) {
        float a4 = l3b[tid];
        for (int aa = 0; aa < H3; ++aa) a4 += tmpv[aa] * l3w[aa*H3 + tid];
        red[tid] = tanhf(a4);                      // h4
    }
    __syncthreads();
    if (tid < H4) {
        float a5 = l4b[tid];
        for (int aa = 0; aa < H3; ++aa) a5 += red[aa] * l4w[aa*H4 + tid];
        gate[tid] = tanhf(a5);                     // h5
    }
    __syncthreads();
    if (tid == 0) {
        float zo = l5b[0];
        for (int aa = 0; aa < H4; ++aa) zo += gate[aa] * l5w[aa];
        out[s] = 1.0f / (1.0f + expf(-zo));
    }
}

extern "C" void kernel_launch(void* const* d_in, const int* in_sizes, int n_in,
                              void* d_out, int out_size, void* d_ws, size_t ws_size,
                              hipStream_t stream)
{
    const float* A   = (const float*)d_in[0];
    const float* x   = (const float*)d_in[1];
    const float* w1  = (const float*)d_in[2];
    const float* lw1 = (const float*)d_in[3];
    const float* lb1 = (const float*)d_in[4];
    const float* w2  = (const float*)d_in[5];
    const float* lw2 = (const float*)d_in[6];
    const float* lb2 = (const float*)d_in[7];
    const float* gw  = (const float*)d_in[8];
    const float* gb  = (const float*)d_in[9];
    const float* nw  = (const float*)d_in[10];
    const float* nb  = (const float*)d_in[11];
    const float* l3w = (const float*)d_in[12];
    const float* l3b = (const float*)d_in[13];
    const float* l4w = (const float*)d_in[14];
    const float* l4b = (const float*)d_in[15];
    const float* l5w = (const float*)d_in[16];
    const float* l5b = (const float*)d_in[17];
    float* out = (float*)d_out;
    unsigned short* wp = (unsigned short*)d_ws;   // 53,248 bf16 = 106,496 B

    pack_weights<<<104, 512, 0, stream>>>(w1, lw1, w2, lw2, nw, wp);
    fused_kernel<<<SN, 512, 0, stream>>>(A, x, wp, lb1, lb2, gw, gb, nb,
                                         l3w, l3b, l4w, l4b, l5w, l5b, out);
}

// Round 6
// 111.126 us; speedup vs baseline: 1.1176x; 1.1176x over previous
//
#include <hip/hip_runtime.h>
#include <math.h>

#define SN  512
#define NN  128
#define CIN 32
#define CA  5
#define HH  64
#define YY  96
#define H3  128
#define H4  64
#define EPSF 1e-7f

typedef __attribute__((ext_vector_type(8))) short  bf16x8;
typedef __attribute__((ext_vector_type(4))) float  f32x4;
typedef __attribute__((ext_vector_type(4))) unsigned short us4;

__device__ inline unsigned short f2b(float f) {
    unsigned u = __builtin_bit_cast(unsigned, f);
    return (unsigned short)((u + 0x7FFFu + ((u >> 16) & 1u)) >> 16);
}
__device__ inline float b2f(unsigned short h) {
    unsigned u = ((unsigned)h) << 16;
    return __builtin_bit_cast(float, u);
}
__device__ inline bf16x8 pack8(float4 f0, float4 f1) {
    bf16x8 v;
    v[0]=(short)f2b(f0.x); v[1]=(short)f2b(f0.y); v[2]=(short)f2b(f0.z); v[3]=(short)f2b(f0.w);
    v[4]=(short)f2b(f1.x); v[5]=(short)f2b(f1.y); v[6]=(short)f2b(f1.z); v[7]=(short)f2b(f1.w);
    return v;
}

// PZ: 320 rows (c0..c4 x 64 b) x 128 shorts, XOR-swizzled 16B chunks.
__device__ inline void pz_store4(short* PZ, int row, int colsh, const f32x4& pc) {
    int byo = (colsh*2) ^ ((row & 7) << 4);
    us4 w;
    w[0]=f2b(pc[0]); w[1]=f2b(pc[1]); w[2]=f2b(pc[2]); w[3]=f2b(pc[3]);
    *(us4*)&PZ[row*128 + (byo >> 1)] = w;
}
__device__ inline bf16x8 pz_load8(const short* PZ, int row, int colsh) {
    int byo = (colsh*2) ^ ((row & 7) << 4);
    return *(const bf16x8*)&PZ[row*128 + (byo >> 1)];
}
__device__ inline float pz_load1(const short* PZ, int row, int colsh) {
    int byo = (colsh*2) ^ ((row & 7) << 4);
    return b2f((unsigned short)PZ[row*128 + (byo >> 1)]);
}

// ws pack (bf16): W1p [c5][b64][a32] @0 | W2p [c5][b64][a96] @10240 | nwp [b128][a96] @40960
__global__ __launch_bounds__(512) void pack_weights(
    const float* __restrict__ w1, const float* __restrict__ lw1,
    const float* __restrict__ w2, const float* __restrict__ lw2,
    const float* __restrict__ nw, unsigned short* __restrict__ wp)
{
    int t = blockIdx.x*512 + threadIdx.x;
    if (t < 10240) {
        int c = t >> 11, rem = t & 2047, b = rem >> 5, a = rem & 31;
        float v = (c < 4) ? w1[(a*64+b)*4 + c] : lw1[a*64+b];
        wp[t] = f2b(v);
    } else if (t < 40960) {
        int u = t - 10240;
        int c = u / 6144, rem = u % 6144, b = rem / 96, a = rem % 96;
        float v = (c < 4) ? w2[(a*64+b)*4 + c] : lw2[a*64+b];
        wp[t] = f2b(v);
    } else {
        int u = t - 40960;
        int b = u / 96, a = u % 96;
        wp[t] = f2b(nw[a*128 + b]);
    }
}

// One conv stage with c-split wave pairs: wave (p, h) owns i/j-tile p and
// channels {2h, 2h+1}; h0 additionally computes the linear channel (c=4).
// v[n][r] valid on h==0 waves only.
template<int CINY, bool FIRST>
__device__ __forceinline__ void conv_core(
    const unsigned short* __restrict__ wp, const float* __restrict__ LB,
    short* PZ, float* PART, const bf16x8 (&Af)[4][2],
    bf16x8 y0, bf16x8 y1, bf16x8 y2,
    float (&inv)[2][4], float (&v)[4][4],
    int p, int h, int lm, int kg)
{
    constexpr int K32  = CINY / 32;
    constexpr int WOFF = (CINY == 32) ? 0 : 10240;
    bf16x8 yf[3] = {y0, y1, y2};

    // ---- P GEMM: h0 -> c {0,1,4}; h1 -> c {2,3} ----
    #pragma unroll
    for (int cl = 0; cl < 3; ++cl) {
        if (h && cl == 2) continue;
        const int c = h ? 2 + cl : (cl == 2 ? 4 : cl);
        f32x4 pc[4];
        #pragma unroll
        for (int n = 0; n < 4; ++n) pc[n] = (f32x4){0.f,0.f,0.f,0.f};
        #pragma unroll
        for (int ks = 0; ks < K32; ++ks) {
            #pragma unroll
            for (int n = 0; n < 4; ++n) {
                const bf16x8 bw = *(const bf16x8*)&wp[WOFF + (c*64 + n*16 + lm)*CINY + ks*32 + kg*8];
                pc[n] = __builtin_amdgcn_mfma_f32_16x16x32_bf16(yf[ks], bw, pc[n], 0,0,0);
            }
        }
        #pragma unroll
        for (int n = 0; n < 4; ++n)
            pz_store4(PZ, c*64 + n*16 + lm, p*16 + kg*4, pc[n]);
    }
    __syncthreads();

    // ---- main GEMM over A: each half does its 2 channels ----
    f32x4 acc[2][4];
    #pragma unroll
    for (int cl=0;cl<2;++cl)
        #pragma unroll
        for (int n=0;n<4;++n) acc[cl][n] = (f32x4){0.f,0.f,0.f,0.f};
    f32x4 sums[2];
    if constexpr (FIRST) {
        #pragma unroll
        for (int cl=0;cl<2;++cl) sums[cl] = (f32x4){0.f,0.f,0.f,0.f};
    }
    bf16x8 ones;
    #pragma unroll
    for (int q=0;q<8;++q) ones[q] = (short)0x3F80;

    #pragma unroll
    for (int jt = 0; jt < 4; ++jt) {
        #pragma unroll
        for (int cl = 0; cl < 2; ++cl) {
            const int row0 = (2*h + cl)*64;
            #pragma unroll
            for (int n = 0; n < 4; ++n) {
                const bf16x8 bp = pz_load8(PZ, row0 + n*16 + lm, jt*32 + kg*8);
                acc[cl][n] = __builtin_amdgcn_mfma_f32_16x16x32_bf16(Af[jt][cl], bp, acc[cl][n], 0,0,0);
            }
            if constexpr (FIRST)
                sums[cl] = __builtin_amdgcn_mfma_f32_16x16x32_bf16(Af[jt][cl], ones, sums[cl], 0,0,0);
        }
    }
    if constexpr (FIRST) {
        #pragma unroll
        for (int cl=0;cl<2;++cl)
            #pragma unroll
            for (int r=0;r<4;++r) inv[cl][r] = 1.0f/(sums[cl][r] + EPSF);
    }

    if (h) {   // write partial (channels 2,3)
        #pragma unroll
        for (int n=0;n<4;++n)
            #pragma unroll
            for (int r=0;r<4;++r)
                PART[p*1024 + (kg*4+r)*64 + n*16 + lm] =
                    acc[0][n][r]*inv[0][r] + acc[1][n][r]*inv[1][r];
    }
    __syncthreads();
    if (!h) {  // combine: own channels 0,1 + partner's partial + linear + bias
        #pragma unroll
        for (int n=0;n<4;++n) {
            const int b = n*16 + lm;
            const float lbv = LB[b];
            #pragma unroll
            for (int r=0;r<4;++r) {
                const int i = p*16 + kg*4 + r;
                float vv = lbv
                    + acc[0][n][r]*inv[0][r] + acc[1][n][r]*inv[1][r]
                    + PART[p*1024 + (kg*4+r)*64 + b]
                    + pz_load1(PZ, 256 + b, i);
                v[n][r] = tanhf(vv);
            }
        }
    }
}

__global__ __launch_bounds__(1024) void fused_kernel(
    const float* __restrict__ A, const float* __restrict__ x,
    const unsigned short* __restrict__ wp,
    const float* __restrict__ lb1, const float* __restrict__ lb2,
    const float* __restrict__ gw, const float* __restrict__ gb,
    const float* __restrict__ nb,
    const float* __restrict__ l3w, const float* __restrict__ l3b,
    const float* __restrict__ l4w, const float* __restrict__ l4b,
    const float* __restrict__ l5w, const float* __restrict__ l5b,
    float* __restrict__ out)
{
    __shared__ __align__(16) char smem[133120];
    short* PZ   = (short*)smem;                    // 320 rows x 128 sh = 81,920 B
    short* H1   = (short*)(smem + 81920);          // [128][72] sh     = 18,432 B
    float* PART = (float*)(smem + 100352);         // [8][16][64] f32  = 32,768 B
    // pool aliases (PZ dead by then)
    short* xcb  = (short*)smem;                    // [128][104] bf16
    float* part = PART;                            // [16][128] f32
    float* gate = (float*)(smem + 100352 + 8192);
    float* red  = (float*)(smem + 100352 + 8704);
    float* tmpv = (float*)(smem + 100352 + 9216);

    const int s = blockIdx.x, tid = threadIdx.x;
    const int wave = tid>>6, lane = tid&63, lm = lane&15, kg = lane>>4;
    const int p = wave >> 1, h = wave & 1;
    const float* xg = x + (size_t)s*NN*CIN;

    // x fragment (j-row = p*16 + lm) for P-GEMMs
    const int jrow = p*16 + lm;
    bf16x8 xfrag;
    {
        float4 f0 = *(const float4*)(xg + jrow*CIN + kg*8);
        float4 f1 = *(const float4*)(xg + jrow*CIN + kg*8 + 4);
        xfrag = pack8(f0, f1);
    }

    // ===== A prepass: coalesced float4 -> pair-shared dbuf LDS -> Af[jt][cl] =====
    bf16x8 Af[4][2];
    {
        const float* Ab = A + ((size_t)s*NN + p*16)*NN*CA;
        const int r8 = lane>>3, l8 = lane&7;
        const int r = r8 + 8*h;                     // this wave's 8 rows of the tile
        #pragma unroll
        for (int jt = 0; jt < 4; ++jt) {
            short* buf = (short*)smem + p*5376 + (jt & 1)*2688;   // [16][168]
            {
                const float* rp = Ab + (size_t)r*(NN*CA) + jt*160 + l8*20;
                float4 q0 = *(const float4*)(rp);
                float4 q1 = *(const float4*)(rp+4);
                float4 q2 = *(const float4*)(rp+8);
                float4 q3 = *(const float4*)(rp+12);
                float4 q4 = *(const float4*)(rp+16);
                short* lr = buf + r*168;
                const int jb = 4*l8;
                lr[0*40 + jb+0] = (short)f2b(q0.x);
                lr[1*40 + jb+0] = (short)f2b(q0.y);
                lr[2*40 + jb+0] = (short)f2b(q0.z);
                lr[3*40 + jb+0] = (short)f2b(q0.w);
                lr[0*40 + jb+1] = (short)f2b(q1.y);
                lr[1*40 + jb+1] = (short)f2b(q1.z);
                lr[2*40 + jb+1] = (short)f2b(q1.w);
                lr[3*40 + jb+1] = (short)f2b(q2.x);
                lr[0*40 + jb+2] = (short)f2b(q2.z);
                lr[1*40 + jb+2] = (short)f2b(q2.w);
                lr[2*40 + jb+2] = (short)f2b(q3.x);
                lr[3*40 + jb+2] = (short)f2b(q3.y);
                lr[0*40 + jb+3] = (short)f2b(q3.w);
                lr[1*40 + jb+3] = (short)f2b(q4.x);
                lr[2*40 + jb+3] = (short)f2b(q4.y);
                lr[3*40 + jb+3] = (short)f2b(q4.z);
            }
            __syncthreads();
            #pragma unroll
            for (int cl = 0; cl < 2; ++cl)
                Af[jt][cl] = *(const bf16x8*)&buf[lm*168 + (2*h + cl)*40 + kg*8];
        }
    }
    __syncthreads();   // scratch (aliases PZ) fully read before PZ writes

    // ===== conv1 =====
    float inv[2][4];
    float v[4][4];
    conv_core<CIN, true>(wp, lb1, PZ, PART, Af, xfrag, xfrag, xfrag,
                         inv, v, p, h, lm, kg);
    if (!h) {  // h1 -> LDS (bf16, [j][72])
        #pragma unroll
        for (int n=0;n<4;++n)
            #pragma unroll
            for (int r=0;r<4;++r)
                H1[(p*16 + kg*4 + r)*72 + n*16 + lm] = (short)f2b(v[n][r]);
    }
    __syncthreads();   // H1 visible; conv1 PZ/PART reads done

    // ===== conv2 =====
    {
        bf16x8 h0f = *(const bf16x8*)&H1[jrow*72 + kg*8];
        bf16x8 h1f = *(const bf16x8*)&H1[jrow*72 + 32 + kg*8];
        conv_core<YY, false>(wp, lb2, PZ, PART, Af, h0f, h1f, xfrag,
                             inv, v, p, h, lm, kg);
    }
    __syncthreads();   // conv2 reads done -> alias PZ for pool

    // ===== pool + head =====
    if (!h) {
        #pragma unroll
        for (int n=0;n<4;++n)
            #pragma unroll
            for (int r=0;r<4;++r)
                xcb[(p*16 + kg*4 + r)*104 + n*16 + lm] = (short)f2b(v[n][r]);
    }
    for (int t = tid; t < NN*CIN; t += 1024)
        xcb[(t>>5)*104 + 64 + (t&31)] = (short)f2b(xg[t]);
    __syncthreads();

    float z = 0.f, e = 0.f;
    if (tid < NN) {
        z = gb[0];
        for (int a = 0; a < YY; ++a) z += b2f((unsigned short)xcb[tid*104 + a]) * gw[a];
        red[tid] = z;
    }
    __syncthreads();
    for (int off = 64; off > 0; off >>= 1) {
        if (tid < off) red[tid] = fmaxf(red[tid], red[tid + off]);
        __syncthreads();
    }
    const float zmax = red[0];
    __syncthreads();
    if (tid < NN) { e = expf(z - zmax); red[tid] = e; }
    __syncthreads();
    for (int off = 64; off > 0; off >>= 1) {
        if (tid < off) red[tid] += red[tid + off];
        __syncthreads();
    }
    const float gsum = red[0];
    __syncthreads();
    if (tid < NN) gate[tid] = e / gsum;
    __syncthreads();

    // pooled GEMM: i-tile = p, halves split the 8 column tiles (4 each)
    {
        f32x4 pacc[4];
        #pragma unroll
        for (int nt=0;nt<4;++nt) pacc[nt] = (f32x4){0.f,0.f,0.f,0.f};
        #pragma unroll
        for (int ks=0;ks<3;++ks) {
            const bf16x8 afp = *(const bf16x8*)&xcb[(p*16+lm)*104 + ks*32 + kg*8];
            #pragma unroll
            for (int nt=0;nt<4;++nt) {
                const int ntg = h*4 + nt;
                const bf16x8 bfp = *(const bf16x8*)&wp[40960 + (ntg*16+lm)*96 + ks*32 + kg*8];
                pacc[nt] = __builtin_amdgcn_mfma_f32_16x16x32_bf16(afp, bfp, pacc[nt], 0,0,0);
            }
        }
        #pragma unroll
        for (int nt=0;nt<4;++nt) {
            const int ntg = h*4 + nt;
            const float nbv = nb[ntg*16+lm];
            float pv = 0.f;
            #pragma unroll
            for (int r=0;r<4;++r)
                pv += gate[p*16 + kg*4 + r] * tanhf(pacc[nt][r] + nbv);
            pv += __shfl_xor(pv, 16);
            pv += __shfl_xor(pv, 32);
            if (lane < 16) part[wave*128 + ntg*16 + lm] = pv;
        }
    }
    __syncthreads();
    if (tid < H3) {
        const int ht = tid >> 6;
        float pooled = 0.f;
        #pragma unroll
        for (int pp = 0; pp < 8; ++pp) pooled += part[(pp*2 + ht)*128 + tid];
        tmpv[tid] = tanhf(pooled);                 // h3
    }
    __syncthreads();
    if (tid < H3) {
        float a4 = l3b[tid];
        for (int aa = 0; aa < H3; ++aa) a4 += tmpv[aa] * l3w[aa*H3 + tid];
        red[tid] = tanhf(a4);                      // h4
    }
    __syncthreads();
    if (tid < H4) {
        float a5 = l4b[tid];
        for (int aa = 0; aa < H3; ++aa) a5 += red[aa] * l4w[aa*H4 + tid];
        gate[tid] = tanhf(a5);                     // h5
    }
    __syncthreads();
    if (tid == 0) {
        float zo = l5b[0];
        for (int aa = 0; aa < H4; ++aa) zo += gate[aa] * l5w[aa];
        out[s] = 1.0f / (1.0f + expf(-zo));
    }
}

extern "C" void kernel_launch(void* const* d_in, const int* in_sizes, int n_in,
                              void* d_out, int out_size, void* d_ws, size_t ws_size,
                              hipStream_t stream)
{
    const float* A   = (const float*)d_in[0];
    const float* x   = (const float*)d_in[1];
    const float* w1  = (const float*)d_in[2];
    const float* lw1 = (const float*)d_in[3];
    const float* lb1 = (const float*)d_in[4];
    const float* w2  = (const float*)d_in[5];
    const float* lw2 = (const float*)d_in[6];
    const float* lb2 = (const float*)d_in[7];
    const float* gw  = (const float*)d_in[8];
    const float* gb  = (const float*)d_in[9];
    const float* nw  = (const float*)d_in[10];
    const float* nb  = (const float*)d_in[11];
    const float* l3w = (const float*)d_in[12];
    const float* l3b = (const float*)d_in[13];
    const float* l4w = (const float*)d_in[14];
    const float* l4b = (const float*)d_in[15];
    const float* l5w = (const float*)d_in[16];
    const float* l5b = (const float*)d_in[17];
    float* out = (float*)d_out;
    unsigned short* wp = (unsigned short*)d_ws;

    pack_weights<<<104, 512, 0, stream>>>(w1, lw1, w2, lw2, nw, wp);
    fused_kernel<<<SN, 1024, 0, stream>>>(A, x, wp, lb1, lb2, gw, gb, nb,
                                          l3w, l3b, l4w, l4b, l5w, l5b, out);
}